// Round 1
// baseline (82.192 us; speedup 1.0000x reference)
//
#include <hip/hip_runtime.h>

#define MAX_DISP 48

// Problem geometry (fixed by reference):
//   n=2, c=32, h=128, w=256
// out[n][c][d][h][x] = (x>=d) ? l[n][c][h][x] - r[n][c][h][x-d] : 1.0f
// out shape (n, c, MAX_DISP, h, w), float32.

constexpr int W = 256;
constexpr int H = 128;

__global__ __launch_bounds__(256) void cost_volume_kernel(
    const float* __restrict__ l,
    const float* __restrict__ r,
    float* __restrict__ out)
{
    // One block per (n*c*h) row; blockIdx.x in [0, 8192)
    const int row = blockIdx.x;          // = nc*H + h
    const int h   = row % H;
    const int nc  = row / H;             // n*C + c

    __shared__ float rs[W];

    const int t = threadIdx.x;           // 256 threads
    const float* __restrict__ lrow = l + (size_t)row * W;
    const float* __restrict__ rrow = r + (size_t)row * W;

    rs[t] = rrow[t];
    __syncthreads();

    // This thread owns a 4-float quad at x = xq..xq+3 for d-slices (lane_d + 4k).
    const int lane_d = t >> 6;           // 0..3
    const int xq     = (t & 63) << 2;    // 0,4,...,252

    // l quad held in registers across all 12 passes (aligned 16B load).
    const float4 lv = *reinterpret_cast<const float4*>(lrow + xq);

    // Output base for this (nc, h): out + nc*MAX_DISP*H*W + h*W; stride per d = H*W
    float* __restrict__ obase = out + (size_t)nc * MAX_DISP * H * W + (size_t)h * W;

    #pragma unroll
    for (int dpass = 0; dpass < MAX_DISP; dpass += 4) {
        const int d = dpass + lane_d;
        // Clamped shifted reads from LDS (reference uses clip(shift,0); result
        // at invalid positions is overwritten with 1.0 anyway).
        const float r0 = rs[max(xq + 0 - d, 0)];
        const float r1 = rs[max(xq + 1 - d, 0)];
        const float r2 = rs[max(xq + 2 - d, 0)];
        const float r3 = rs[max(xq + 3 - d, 0)];
        float4 o;
        o.x = (xq + 0 >= d) ? lv.x - r0 : 1.0f;
        o.y = (xq + 1 >= d) ? lv.y - r1 : 1.0f;
        o.z = (xq + 2 >= d) ? lv.z - r2 : 1.0f;
        o.w = (xq + 3 >= d) ? lv.w - r3 : 1.0f;
        *reinterpret_cast<float4*>(obase + (size_t)d * H * W + xq) = o;
    }
}

extern "C" void kernel_launch(void* const* d_in, const int* in_sizes, int n_in,
                              void* d_out, int out_size, void* d_ws, size_t ws_size,
                              hipStream_t stream)
{
    const float* l = (const float*)d_in[0];
    const float* r = (const float*)d_in[1];
    float* out = (float*)d_out;

    // n*c*h = 2*32*128 = 8192 blocks
    const int nRows = 2 * 32 * H;
    cost_volume_kernel<<<nRows, 256, 0, stream>>>(l, r, out);
}